// Round 10
// baseline (54.103 us; speedup 1.0000x reference)
//
#include <hip/hip_runtime.h>
#include <hip/hip_fp16.h>
#include <math.h>

#define TT 8192
#define FF 64
#define TILE 32
#define HALO 50

typedef float f32x4 __attribute__((ext_vector_type(4)));

__device__ __forceinline__ float rcpf(float x) { return __builtin_amdgcn_rcpf(x); }

// ---- prep: wsmH[j*64+i] = half(softmax(W)[i][j]); pwH[j*64+i] = half(PW[i][j]) ----
__global__ void prep_kernel(const float* __restrict__ W, const float* __restrict__ PW,
                            __half* __restrict__ wsmH, __half* __restrict__ pwH) {
    const int lane = threadIdx.x;   // j
    const int wv   = threadIdx.y;   // 0..3
    for (int it = 0; it < 16; ++it) {
        const int r = wv * 16 + it; // i
        float v = W[r * 64 + lane];
        float m = v;
        #pragma unroll
        for (int off = 32; off >= 1; off >>= 1)
            m = fmaxf(m, __shfl_xor(m, off, 64));
        float e = __expf(v - m);
        float s = e;
        #pragma unroll
        for (int off = 32; off >= 1; off >>= 1)
            s += __shfl_xor(s, off, 64);
        wsmH[lane * 64 + r] = __float2half(e * rcpf(s));
        pwH[lane * 64 + r]  = __float2half(PW[r * 64 + lane]);
    }
}

// ---- fused main: 256 thr / 4 waves, 32-row tile, 16 feats/wave (8 per lane-half) ----
__global__ __launch_bounds__(256, 4)
void mcao_main(const float* __restrict__ x,
               const __half* __restrict__ wsmH,
               const __half* __restrict__ pwH,
               const float* __restrict__ pb,
               const float* __restrict__ kap,
               const float* __restrict__ coeffs,
               float* __restrict__ out,
               float* __restrict__ memout) {
    // LDS union (37376 B total -> 4 blocks/CU):
    //   phase A: xs f32 [82][64]              [0, 20992)
    //   phase B: tS f32 [64][33]              [0, 8448)
    //            ux half2 {u,x} [64][34]      [8448, 17152)
    //   phase C: P2 f32 [64][33]              [0, 8448)   (reuses tS)
    //   always:  wS half [64][64]             [20992, 29184)
    //            pwS half [64][64]            [29184, 37376)
    __shared__ __align__(16) char smem[37376];
    float*   xs  = (float*)smem;
    float*   tS  = (float*)smem;
    __half2* ux  = (__half2*)(smem + 8448);
    float*   P2  = (float*)smem;
    __half*  wS  = (__half*)(smem + 20992);
    __half*  pwS = (__half*)(smem + 29184);

    const int tid  = threadIdx.x;
    const int lane = tid & 63;
    const int wv   = tid >> 6;              // 0..3

    // XCD-aware bijective swizzle: 1024 blocks -> 128 consecutive tiles/XCD
    const int sw = ((int)blockIdx.x & 7) * 128 + ((int)blockIdx.x >> 3);
    const int b  = sw >> 8;                 // 0..3
    const int t0 = (sw & 255) * TILE;
    const float* xb = x + (size_t)b * TT * FF;

    // ---- stage xs rows [t0-50, t0+32), wS, pwS ----
    for (int i4 = tid; i4 < (TILE + HALO) * 16; i4 += 256) {
        const int s = i4 >> 4, f4 = i4 & 15, t = t0 - HALO + s;
        f32x4 v = {0.f, 0.f, 0.f, 0.f};
        if (t >= 0) v = *(const f32x4*)(xb + (size_t)t * 64 + f4 * 4);
        *(f32x4*)(&xs[i4 * 4]) = v;
    }
    #pragma unroll
    for (int k = 0; k < 2; ++k) {
        ((f32x4*)wS)[tid + 256 * k]  = ((const f32x4*)wsmH)[tid + 256 * k];
        ((f32x4*)pwS)[tid + 256 * k] = ((const f32x4*)pwH)[tid + 256 * k];
    }
    __syncthreads();                                    // bar1

    // ---- FIR: wave owns rows 8wv..8wv+7 ----
    float macc[8] = {0.f,0.f,0.f,0.f,0.f,0.f,0.f,0.f};
    #pragma unroll
    for (int s = 0; s < 58; ++s) {
        const float xv = xs[(8 * wv + s) * 64 + lane];
        #pragma unroll
        for (int r = 0; r < 8; ++r) {
            const int k = r + 50 - s;
            if (0 <= k && k <= 50) macc[r] = fmaf(coeffs[k], xv, macc[r]);
        }
    }
    #pragma unroll
    for (int r = 0; r < 8; ++r)
        memout[(size_t)(b * TT + t0 + 8 * wv + r) * 64 + lane] = macc[r];

    // ---- t/u/x extraction: thread -> (prow=tid>>3, feats (tid&7)*8..+7) ----
    const int prow = tid >> 3, pfq = tid & 7;
    float tq[8], uq[8], xq[8];
    #pragma unroll
    for (int c4 = 0; c4 < 2; ++c4) {
        const f32x4 xv4 = *(const f32x4*)(&xs[(HALO + prow) * 64 + pfq * 8 + c4 * 4]);
        #pragma unroll
        for (int q = 0; q < 4; ++q) {
            const float xi = xv4[q];
            tq[c4 * 4 + q] = fmaf(-2.f, rcpf(__expf(2.f * xi) + 1.f), 1.f);  // tanh
            uq[c4 * 4 + q] = __expf(-fabsf(xi));                             // e^-|x|
            xq[c4 * 4 + q] = xi;
        }
    }
    __syncthreads();                                    // bar2 (all xs reads done)
    #pragma unroll
    for (int c = 0; c < 8; ++c) {
        const int f = pfq * 8 + c;
        tS[f * 33 + prow] = tq[c];
        ux[f * 34 + prow] = __floats2half2_rn(uq[c], xq[c]);
    }
    __syncthreads();                                    // bar3

    // ---- coupling + proj: lane = (h, row); 8 feats per lane ----
    const int r  = lane & 31;               // row in tile
    const int h  = lane >> 5;
    const int ib = wv * 16 + h * 8;         // first feature
    float ti[8], ui[8];
    #pragma unroll
    for (int q = 0; q < 8; ++q) {
        ti[q] = tS[(ib + q) * 33 + r];
        ui[q] = __low2float(ux[(ib + q) * 34 + r]);
    }

    float cacc[8] = {0,0,0,0,0,0,0,0};
    float pacc[8] = {0,0,0,0,0,0,0,0};
    #pragma unroll 8
    for (int j = 0; j < 64; ++j) {
        const float  tj  = tS[j * 33 + r];              // 32 addrs, 2-lane broadcast
        const __half2 uxj = ux[j * 34 + r];
        const float  ujf = __low2float(uxj);
        const float  xjf = __high2float(uxj);
        __half wh[8], ph[8];
        *(f32x4*)wh = *(const f32x4*)(wS  + j * 64 + ib);   // 2-addr broadcast b128
        *(f32x4*)ph = *(const f32x4*)(pwS + j * 64 + ib);
        #pragma unroll
        for (int q = 0; q < 8; ++q) {
            const float d1 = fmaf(-ti[q], tj, 1.f);     // 1 - ti*tj
            const float d2 = fmaf( ui[q], ujf, 1.f);    // 1 + ui*uj
            const float rr = rcpf(d1 * d2);
            const float s  = (ti[q] - tj) * rr;
            cacc[q] = fmaf(__half2float(wh[q]), s,   cacc[q]);   // v_fma_mix
            pacc[q] = fmaf(__half2float(ph[q]), xjf, pacc[q]);   // v_fma_mix
        }
    }

    const float kappa = kap[0];
    const float ksum  = (1.f - __expf(-kappa * (float)(t0 + r + 1))) *
                        rcpf(1.f - __expf(-kappa));
    __syncthreads();                                    // bar4 (plane reads done)
    #pragma unroll
    for (int q = 0; q < 8; ++q)
        P2[(ib + q) * 33 + r] =
            fmaf(0.4f, cacc[q], 0.3f * (pacc[q] + pb[ib + q]) * ksum);
    __syncthreads();                                    // bar5

    // ---- final store: wave rows 8wv..8wv+7, lane = feature ----
    #pragma unroll
    for (int rr = 0; rr < 8; ++rr) {
        const int row = 8 * wv + rr;
        out[(size_t)(b * TT + t0 + row) * 64 + lane] =
            fmaf(0.3f, macc[rr], P2[lane * 33 + row]);  // 2-way banks: free
    }
}

extern "C" void kernel_launch(void* const* d_in, const int* in_sizes, int n_in,
                              void* d_out, int out_size, void* d_ws, size_t ws_size,
                              hipStream_t stream) {
    const float* x   = (const float*)d_in[0];
    const float* W   = (const float*)d_in[1];
    const float* PW  = (const float*)d_in[2];
    const float* pb  = (const float*)d_in[3];
    const float* kap = (const float*)d_in[4];
    const float* cf  = (const float*)d_in[5];

    float* out    = (float*)d_out;
    float* memout = out + (size_t)4 * TT * FF;

    __half* wsmH = (__half*)d_ws;            // 8 KB
    __half* pwH  = wsmH + 64 * 64;           // 8 KB

    hipLaunchKernelGGL(prep_kernel, dim3(1), dim3(64, 4), 0, stream, W, PW, wsmH, pwH);
    hipLaunchKernelGGL(mcao_main, dim3(4 * (TT / TILE)), dim3(256), 0, stream,
                       x, wsmH, pwH, pb, kap, cf, out, memout);
}

// Round 11
// 48.418 us; speedup vs baseline: 1.1174x; 1.1174x over previous
//
#include <hip/hip_runtime.h>
#include <hip/hip_fp16.h>
#include <math.h>

#define TT 8192
#define FF 64
#define TILE 64
#define HALO 50

typedef float f32x2 __attribute__((ext_vector_type(2)));
typedef float f32x4 __attribute__((ext_vector_type(4)));

__device__ __forceinline__ float rcpf(float x) { return __builtin_amdgcn_rcpf(x); }

// ---- prep: wsmT[j*64+i] = softmax(W)[i][j] (f32); pwT[j*64+i] = PW[i][j] (f32) ----
__global__ void prep_kernel(const float* __restrict__ W, const float* __restrict__ PW,
                            float* __restrict__ wsmT, float* __restrict__ pwT) {
    const int lane = threadIdx.x;   // j
    const int wv   = threadIdx.y;   // 0..3
    for (int it = 0; it < 16; ++it) {
        const int r = wv * 16 + it; // i
        float v = W[r * 64 + lane];
        float m = v;
        #pragma unroll
        for (int off = 32; off >= 1; off >>= 1)
            m = fmaxf(m, __shfl_xor(m, off, 64));
        float e = __expf(v - m);
        float s = e;
        #pragma unroll
        for (int off = 32; off >= 1; off >>= 1)
            s += __shfl_xor(s, off, 64);
        wsmT[lane * 64 + r] = e * rcpf(s);
        pwT[lane * 64 + r]  = PW[r * 64 + lane];
    }
}

// ---- fused main: 1024 thr / 16 waves, 64-row tile; wave = 4 feats, lane = row ----
__global__ __launch_bounds__(1024, 8)
void mcao_main(const float* __restrict__ x,
               const float* __restrict__ wsmT,
               const float* __restrict__ pwT,
               const float* __restrict__ pb,
               const float* __restrict__ kap,
               const float* __restrict__ coeffs,
               float* __restrict__ out,
               float* __restrict__ memout) {
    // LDS (66048 B -> 2 blocks/CU = 32 waves/CU):
    //   region A [0,33280): union{ xs f32 [114][64] (29184) ;
    //                              tux f32x2 [64][65] {t, half2{u,x}} (33280) ;
    //                              P2 f32 [64][65] (16640, after j-loop) }
    //   wS  f32 [64][64]  at 33280
    //   pwS f32 [64][64]  at 49664
    __shared__ __align__(16) char smem[66048];
    float* xs  = (float*)smem;
    f32x2* tux = (f32x2*)smem;
    float* P2  = (float*)smem;
    float* wS  = (float*)(smem + 33280);
    float* pwS = (float*)(smem + 49664);

    const int tid  = threadIdx.x;
    const int lane = tid & 63;
    const int wv   = tid >> 6;              // 0..15

    // XCD-aware bijective swizzle: 512 blocks -> 64 consecutive tiles per XCD
    const int sw = ((int)blockIdx.x & 7) * 64 + ((int)blockIdx.x >> 3);
    const int b  = sw >> 7;                 // 0..3
    const int t0 = (sw & 127) * TILE;
    const float* xb = x + (size_t)b * TT * FF;

    // ---- stage xs rows [t0-50, t0+64) f32, wS, pwS ----
    #pragma unroll
    for (int k = 0; k < 2; ++k) {
        const int i4 = tid + 1024 * k;
        if (i4 < 114 * 16) {
            const int s = i4 >> 4, f4 = i4 & 15, t = t0 - HALO + s;
            f32x4 v = {0.f, 0.f, 0.f, 0.f};
            if (t >= 0) v = *(const f32x4*)(xb + (size_t)t * 64 + f4 * 4);
            *(f32x4*)(&xs[s * 64 + f4 * 4]) = v;
        }
    }
    ((f32x4*)wS)[tid]  = ((const f32x4*)wsmT)[tid];
    ((f32x4*)pwS)[tid] = ((const f32x4*)pwT)[tid];
    __syncthreads();                                    // bar1

    // ---- FIR: wave owns rows 4wv..4wv+3 (lane = feature) ----
    float macc[4] = {0.f, 0.f, 0.f, 0.f};
    #pragma unroll
    for (int s = 0; s < 54; ++s) {
        const float xv = xs[(4 * wv + s) * 64 + lane];
        #pragma unroll
        for (int r = 0; r < 4; ++r) {
            const int k = r + 50 - s;
            if (0 <= k && k <= 50) macc[r] = fmaf(coeffs[k], xv, macc[r]);
        }
    }
    #pragma unroll
    for (int r = 0; r < 4; ++r)
        memout[(size_t)(b * TT + t0 + 4 * wv + r) * 64 + lane] = macc[r];

    // ---- extraction: thread -> (row = tid>>4, feats f0..f0+3) ----
    const int erow = tid >> 4, f0 = (tid & 15) * 4;
    const f32x4 xv4 = *(const f32x4*)(&xs[(HALO + erow) * 64 + f0]);
    float tq[4]; unsigned pk[4];
    #pragma unroll
    for (int q = 0; q < 4; ++q) {
        const float xi = xv4[q];
        tq[q] = fmaf(-2.f, rcpf(__expf(2.f * xi) + 1.f), 1.f);      // tanh
        const float uu = __expf(-fabsf(xi));                        // e^-|x|
        pk[q] = (unsigned)__half_as_ushort(__float2half_rn(xi)) << 16 |
                (unsigned)__half_as_ushort(__float2half_rn(uu));    // {hi:x, lo:u}
    }
    __syncthreads();                                    // bar2 (all xs reads done)
    #pragma unroll
    for (int q = 0; q < 4; ++q) {
        f32x2 e; e.x = tq[q]; e.y = __uint_as_float(pk[q]);
        tux[(f0 + q) * 65 + erow] = e;
    }
    __syncthreads();                                    // bar3

    // ---- coupling + proj: lane = row r; wave's 4 feats ib..ib+3 ----
    const int r  = lane;
    const int ib = __builtin_amdgcn_readfirstlane(wv) * 4;   // SGPR -> uniform LDS addr

    f32x2 tiP[2], uiP[2];
    #pragma unroll
    for (int q = 0; q < 4; ++q) {
        const f32x2 e = tux[(ib + q) * 65 + r];
        const unsigned u = __float_as_uint(e.y);
        tiP[q >> 1][q & 1] = e.x;
        uiP[q >> 1][q & 1] = __half2float(__ushort_as_half((unsigned short)(u & 0xFFFF)));
    }

    f32x2 cac[2] = {{0.f, 0.f}, {0.f, 0.f}};
    f32x2 pac[2] = {{0.f, 0.f}, {0.f, 0.f}};
    const f32x2 one2 = {1.f, 1.f};
    #pragma unroll 8
    for (int j = 0; j < 64; ++j) {
        const f32x2 e = tux[j * 65 + r];                 // per-lane b64, conflict-free
        const unsigned u = __float_as_uint(e.y);
        const float tj = e.x;
        const float uj = __half2float(__ushort_as_half((unsigned short)(u & 0xFFFF)));
        const float xj = __half2float(__ushort_as_half((unsigned short)(u >> 16)));
        const f32x4 w4 = *(const f32x4*)(wS  + j * 64 + ib);   // 1-addr broadcast
        const f32x4 p4 = *(const f32x4*)(pwS + j * 64 + ib);   // 1-addr broadcast
        const f32x2 tjj = {tj, tj}, ujj = {uj, uj}, xjj = {xj, xj};
        #pragma unroll
        for (int g = 0; g < 2; ++g) {
            const f32x2 d1  = __builtin_elementwise_fma(-tiP[g], tjj, one2); // pk_fma
            const f32x2 d2  = __builtin_elementwise_fma( uiP[g], ujj, one2); // pk_fma
            const f32x2 den = d1 * d2;                                       // pk_mul
            f32x2 rr; rr.x = rcpf(den.x); rr.y = rcpf(den.y);
            const f32x2 s = (tiP[g] - tjj) * rr;                             // pk
            f32x2 wg; wg.x = w4[2 * g]; wg.y = w4[2 * g + 1];
            f32x2 pg; pg.x = p4[2 * g]; pg.y = p4[2 * g + 1];
            cac[g] = __builtin_elementwise_fma(s,   wg, cac[g]);             // pk_fma
            pac[g] = __builtin_elementwise_fma(xjj, pg, pac[g]);             // pk_fma
        }
    }

    // ---- epilogue ----
    const float kappa  = kap[0];
    const float inv1mr = rcpf(1.f - __expf(-kappa));
    const float ksum   = (1.f - __expf(-kappa * (float)(t0 + r + 1))) * inv1mr;
    const f32x4 pbv    = *(const f32x4*)(pb + ib);       // uniform
    __syncthreads();                                    // bar4 (tux reads done)
    #pragma unroll
    for (int q = 0; q < 4; ++q) {
        const float cv = (q & 1) ? cac[q >> 1].y : cac[q >> 1].x;
        const float pv = (q & 1) ? pac[q >> 1].y : pac[q >> 1].x;
        P2[(ib + q) * 65 + r] = fmaf(0.4f, cv, 0.3f * (pv + pbv[q]) * ksum);
    }
    __syncthreads();                                    // bar5

    // ---- final store: wave rows 4wv..4wv+3, lane = feature (coalesced) ----
    #pragma unroll
    for (int rr2 = 0; rr2 < 4; ++rr2) {
        const int row = 4 * wv + rr2;
        out[(size_t)(b * TT + t0 + row) * 64 + lane] =
            fmaf(0.3f, macc[rr2], P2[lane * 65 + row]);  // (lane+row)%32 distinct: free
    }
}

extern "C" void kernel_launch(void* const* d_in, const int* in_sizes, int n_in,
                              void* d_out, int out_size, void* d_ws, size_t ws_size,
                              hipStream_t stream) {
    const float* x   = (const float*)d_in[0];
    const float* W   = (const float*)d_in[1];
    const float* PW  = (const float*)d_in[2];
    const float* pb  = (const float*)d_in[3];
    const float* kap = (const float*)d_in[4];
    const float* cf  = (const float*)d_in[5];

    float* out    = (float*)d_out;
    float* memout = out + (size_t)4 * TT * FF;

    float* wsmT = (float*)d_ws;          // 16 KB
    float* pwT  = wsmT + 64 * 64;        // 16 KB

    hipLaunchKernelGGL(prep_kernel, dim3(1), dim3(64, 4), 0, stream, W, PW, wsmT, pwT);
    hipLaunchKernelGGL(mcao_main, dim3(4 * (TT / TILE)), dim3(1024), 0, stream,
                       x, wsmT, pwT, pb, kap, cf, out, memout);
}

// Round 12
// 45.365 us; speedup vs baseline: 1.1926x; 1.0673x over previous
//
#include <hip/hip_runtime.h>
#include <hip/hip_fp16.h>
#include <math.h>

#define TT 8192
#define FF 64
#define TILE 32
#define HALO 50

typedef float f32x2 __attribute__((ext_vector_type(2)));
typedef float f32x4 __attribute__((ext_vector_type(4)));
typedef _Float16 f16x8 __attribute__((ext_vector_type(8)));
typedef unsigned int u32x4 __attribute__((ext_vector_type(4)));

__device__ __forceinline__ float rcpf(float x) { return __builtin_amdgcn_rcpf(x); }

// ---- prep: softmax(W) transposed to wsmT[j*64+i]; PW -> precomputed f16 B-fragments ----
// B-frag layout for mfma_f32_16x16x32_f16: lane holds B[k=(lane>>4)*8+q][col=lane&15],
// with B[k][col] = PW[n*16+col][k]  (proj = X @ PW^T). Slot (n*2+kt)*64+lane, kt = k/32.
__global__ void prep_kernel(const float* __restrict__ W, const float* __restrict__ PW,
                            float* __restrict__ wsmT, u32x4* __restrict__ pwB) {
    const int lane = threadIdx.x;   // j
    const int wv   = threadIdx.y;   // 0..3
    const int tid  = wv * 64 + lane;
    for (int it = 0; it < 16; ++it) {
        const int r = wv * 16 + it; // i
        float v = W[r * 64 + lane];
        float m = v;
        #pragma unroll
        for (int off = 32; off >= 1; off >>= 1)
            m = fmaxf(m, __shfl_xor(m, off, 64));
        float e = __expf(v - m);
        float s = e;
        #pragma unroll
        for (int off = 32; off >= 1; off >>= 1)
            s += __shfl_xor(s, off, 64);
        wsmT[lane * 64 + r] = e * rcpf(s);
    }
    for (int s = tid; s < 512; s += 256) {
        const int n2 = s >> 6;                       // n = n2>>1, kt = n2&1
        const int ln = s & 63;
        const int i  = (n2 >> 1) * 16 + (ln & 15);   // output col (feature i)
        const int k0 = (n2 & 1) * 32 + (ln >> 4) * 8;
        u32x4 frag;
        #pragma unroll
        for (int w = 0; w < 4; ++w) {
            const unsigned lo = __half_as_ushort(__float2half_rn(PW[i * 64 + k0 + 2 * w]));
            const unsigned hi = __half_as_ushort(__float2half_rn(PW[i * 64 + k0 + 2 * w + 1]));
            frag[w] = lo | (hi << 16);
        }
        pwB[s] = frag;
    }
}

// ---- fused main: 512 thr / 8 waves, 32-row tile ----
__global__ __launch_bounds__(512, 4)
void mcao_main(const float* __restrict__ x,
               const float* __restrict__ wsmT,
               const u32x4* __restrict__ pwB,
               const float* __restrict__ pb,
               const float* __restrict__ kap,
               const float* __restrict__ coeffs,
               float* __restrict__ out,
               float* __restrict__ memout) {
    // LDS (40960 B exactly -> 4 blocks/CU = 32 waves/CU):
    //   [0,20992)      xs f32 [82][64]        (staging/FIR/extraction/MFMA-A phase)
    //   [0,16384)      tux f32x2 [64][32]     {t,u} planes (after bar2)
    //   [16384,24576)  P2 f32 [64][32]        XOR-swizzled (proj then final bracket)
    //   [24576,40960)  wS f32 [64][64]        softmax(W)[i][j] at [j*64+i]
    __shared__ __align__(16) char smem[40960];
    float* xs  = (float*)smem;
    f32x2* tux = (f32x2*)smem;
    float* P2  = (float*)(smem + 16384);
    float* wS  = (float*)(smem + 24576);

    const int tid  = threadIdx.x;
    const int lane = tid & 63;
    const int wv   = tid >> 6;              // 0..7

    // XCD-aware bijective swizzle: 1024 blocks -> 128 consecutive tiles per XCD
    const int sw = ((int)blockIdx.x & 7) * 128 + ((int)blockIdx.x >> 3);
    const int b  = sw >> 8;                 // 0..3
    const int t0 = (sw & 255) * TILE;
    const float* xb = x + (size_t)b * TT * FF;

    // ---- stage xs rows [t0-50, t0+32) and wS ----
    for (int i4 = tid; i4 < 82 * 16; i4 += 512) {
        const int s = i4 >> 4, f4 = i4 & 15, t = t0 - HALO + s;
        f32x4 v = {0.f, 0.f, 0.f, 0.f};
        if (t >= 0) v = *(const f32x4*)(xb + (size_t)t * 64 + f4 * 4);
        *(f32x4*)(&xs[i4 * 4]) = v;
    }
    ((f32x4*)wS)[tid]       = ((const f32x4*)wsmT)[tid];
    ((f32x4*)wS)[tid + 512] = ((const f32x4*)wsmT)[tid + 512];
    __syncthreads();                                    // bar1

    // ---- FIR: wave owns rows 4wv..4wv+3 (lane = feature) ----
    float macc[4] = {0.f, 0.f, 0.f, 0.f};
    #pragma unroll
    for (int s = 0; s < 54; ++s) {
        const float xv = xs[(4 * wv + s) * 64 + lane];
        #pragma unroll
        for (int r = 0; r < 4; ++r) {
            const int k = r + 50 - s;
            if (0 <= k && k <= 50) macc[r] = fmaf(coeffs[k], xv, macc[r]);
        }
    }
    #pragma unroll
    for (int r = 0; r < 4; ++r)
        memout[(size_t)(b * TT + t0 + 4 * wv + r) * 64 + lane] = macc[r];

    // ---- extraction (regs): thread -> (row = tid>>4, feats (tid&15)*4..+3) ----
    const int erow = tid >> 4, f0 = (tid & 15) * 4;
    const f32x4 xv4 = *(const f32x4*)(&xs[(HALO + erow) * 64 + f0]);
    f32x2 tu[4];
    #pragma unroll
    for (int q = 0; q < 4; ++q) {
        const float xi = xv4[q];
        tu[q].x = fmaf(-2.f, rcpf(__expf(2.f * xi) + 1.f), 1.f);  // tanh
        tu[q].y = __expf(-fabsf(xi));                             // e^-|x|
    }

    // ---- proj via MFMA: wave -> tile (mt = wv>>2, nt = wv&3) ----
    const int mt = wv >> 2, nt = wv & 3;
    const int arow = HALO + mt * 16 + (lane & 15);
    const int kcol = (lane >> 4) * 8;
    f32x4 cfr = {0.f, 0.f, 0.f, 0.f};
    #pragma unroll
    for (int kt = 0; kt < 2; ++kt) {
        const f32x4 alo = *(const f32x4*)(&xs[arow * 64 + kt * 32 + kcol]);
        const f32x4 ahi = *(const f32x4*)(&xs[arow * 64 + kt * 32 + kcol + 4]);
        f16x8 afr;
        #pragma unroll
        for (int q = 0; q < 4; ++q) {
            afr[q]     = (_Float16)alo[q];
            afr[q + 4] = (_Float16)ahi[q];
        }
        const u32x4 bw = pwB[(nt * 2 + kt) * 64 + lane];
        const f16x8 bfr = __builtin_bit_cast(f16x8, bw);
        cfr = __builtin_amdgcn_mfma_f32_16x16x32_f16(afr, bfr, cfr, 0, 0, 0);
    }
    __syncthreads();                                    // bar2 (all xs reads done)

    // ---- write planes ----
    #pragma unroll
    for (int q = 0; q < 4; ++q)
        tux[(f0 + q) * 32 + erow] = tu[q];
    {   // proj C-frag -> P2 (xor-swizzled): col = nt*16+(lane&15), row = mt*16+(lane>>4)*4+reg
        const int ic = nt * 16 + (lane & 15);
        const int rbase = mt * 16 + (lane >> 4) * 4;
        #pragma unroll
        for (int reg = 0; reg < 4; ++reg) {
            const int rr = rbase + reg;
            P2[ic * 32 + (rr ^ (ic & 31))] = cfr[reg];
        }
    }
    __syncthreads();                                    // bar3

    // ---- coupling: lane = (h, r); 4 feats per lane, ib = wv*8 + h*4 ----
    const int r  = lane & 31;
    const int h  = lane >> 5;
    const int ib = wv * 8 + h * 4;
    f32x2 tiP[2], uiP[2];
    #pragma unroll
    for (int q = 0; q < 4; ++q) {
        const f32x2 e = tux[(ib + q) * 32 + r];
        tiP[q >> 1][q & 1] = e.x;
        uiP[q >> 1][q & 1] = e.y;
    }

    f32x2 cac0 = {0.f, 0.f}, cac1 = {0.f, 0.f};
    const f32x2 one2 = {1.f, 1.f};
    #pragma unroll 8
    for (int j = 0; j < 64; ++j) {
        const f32x2 e  = tux[j * 32 + r];               // b64, 2-way broadcast: free
        const f32x4 w4 = *(const f32x4*)(&wS[j * 64 + ib]);  // 2-addr b128 broadcast
        const f32x2 tjj = {e.x, e.x}, ujj = {e.y, e.y};
        {
            const f32x2 d1  = __builtin_elementwise_fma(-tiP[0], tjj, one2);
            const f32x2 d2  = __builtin_elementwise_fma( uiP[0], ujj, one2);
            const f32x2 den = d1 * d2;
            f32x2 rr0; rr0.x = rcpf(den.x); rr0.y = rcpf(den.y);
            const f32x2 s0 = (tiP[0] - tjj) * rr0;
            f32x2 w0; w0.x = w4[0]; w0.y = w4[1];
            cac0 = __builtin_elementwise_fma(s0, w0, cac0);
        }
        {
            const f32x2 d1  = __builtin_elementwise_fma(-tiP[1], tjj, one2);
            const f32x2 d2  = __builtin_elementwise_fma( uiP[1], ujj, one2);
            const f32x2 den = d1 * d2;
            f32x2 rr1; rr1.x = rcpf(den.x); rr1.y = rcpf(den.y);
            const f32x2 s1 = (tiP[1] - tjj) * rr1;
            f32x2 w1; w1.x = w4[2]; w1.y = w4[3];
            cac1 = __builtin_elementwise_fma(s1, w1, cac1);
        }
    }

    // ---- epilogue: P2 <- 0.4c + 0.3(proj+pb)ksum (slot owner RMW, no barrier) ----
    const float kappa = kap[0];
    const float ksum  = (1.f - __expf(-kappa * (float)(t0 + r + 1))) *
                        rcpf(1.f - __expf(-kappa));
    const f32x4 pbv = *(const f32x4*)(pb + ib);
    #pragma unroll
    for (int q = 0; q < 4; ++q) {
        const float cv = (q & 1) ? ((q >> 1) ? cac1.y : cac0.y)
                                 : ((q >> 1) ? cac1.x : cac0.x);
        const int ic  = ib + q;
        const int idx = ic * 32 + (r ^ (ic & 31));
        P2[idx] = fmaf(0.4f, cv, 0.3f * (P2[idx] + pbv[q]) * ksum);
    }
    __syncthreads();                                    // bar4

    // ---- final store: wave rows 4wv..4wv+3, lane = feature (coalesced) ----
    #pragma unroll
    for (int rr2 = 0; rr2 < 4; ++rr2) {
        const int row = 4 * wv + rr2;
        out[(size_t)(b * TT + t0 + row) * 64 + lane] =
            fmaf(0.3f, macc[rr2], P2[lane * 32 + (row ^ (lane & 31))]);
    }
}

extern "C" void kernel_launch(void* const* d_in, const int* in_sizes, int n_in,
                              void* d_out, int out_size, void* d_ws, size_t ws_size,
                              hipStream_t stream) {
    const float* x   = (const float*)d_in[0];
    const float* W   = (const float*)d_in[1];
    const float* PW  = (const float*)d_in[2];
    const float* pb  = (const float*)d_in[3];
    const float* kap = (const float*)d_in[4];
    const float* cf  = (const float*)d_in[5];

    float* out    = (float*)d_out;
    float* memout = out + (size_t)4 * TT * FF;

    float* wsmT = (float*)d_ws;                          // 16 KB
    u32x4* pwB  = (u32x4*)((char*)d_ws + 16384);         //  8 KB

    hipLaunchKernelGGL(prep_kernel, dim3(1), dim3(64, 4), 0, stream, W, PW, wsmT, pwB);
    hipLaunchKernelGGL(mcao_main, dim3(4 * (TT / TILE)), dim3(512), 0, stream,
                       x, wsmT, pwB, pb, kap, cf, out, memout);
}